// Round 11
// baseline (520.950 us; speedup 1.0000x reference)
//
#include <hip/hip_runtime.h>
#include <cstdint>
#include <cstddef>

// Problem constants
#define Bsz   32
#define Ssz   2048
#define Tsz   768
#define NH    8
#define DH    96
#define DHID  384
#define Ncols (NH*DH)       // 768

using u16 = unsigned short;
typedef __bf16 bf16x8 __attribute__((ext_vector_type(8)));
typedef __bf16 bf16x4 __attribute__((ext_vector_type(4)));
typedef float  f32x4  __attribute__((ext_vector_type(4)));

__device__ __forceinline__ u16 f2bn(float f) {
  __bf16 h = (__bf16)f;
  return __builtin_bit_cast(u16, h);
}
__device__ __forceinline__ float b2f(u16 u) {
  return __builtin_bit_cast(float, (uint32_t)u << 16);
}

// ---------------------------------------------------------------------------
// Kernel 1: pack weights to bf16 (transposed, K-contiguous)  [unchanged]
// ---------------------------------------------------------------------------
__global__ __launch_bounds__(256) void k_pack(const float* __restrict__ Pw,
    const float* __restrict__ W1w, const float* __restrict__ W2w,
    u16* __restrict__ B1t, u16* __restrict__ W1t, u16* __restrict__ W2t)
{
  int i = blockIdx.x * 256 + threadIdx.x;
  if (i < 589824) {
    int n = i / 768, k = i % 768;
    int h = n / 96, d = n % 96;
    B1t[i] = f2bn(Pw[(size_t)h*73728 + (size_t)k*96 + d]);
  } else if (i < 589824 + 294912) {
    int j = i - 589824;
    int h = j / 36864, r = j % 36864;
    int n = r / 96, k = r % 96;
    W1t[j] = f2bn(W1w[(size_t)h*36864 + (size_t)k*384 + n]);
  } else if (i < 589824 + 2*294912) {
    int q = i - 589824 - 294912;
    int h = q / 36864, r = q % 36864;
    int n = r / 384, k = r % 384;
    W2t[q] = f2bn(W2w[(size_t)h*36864 + (size_t)k*96 + n]);
  }
}

// ---------------------------------------------------------------------------
// Kernel 2 (v8, ZERO-LDS): Hi = emb @ B1 + P_b.
// R10 post-mortem: five staged-LDS variants (R4-R10) all converge at
// 175-190us, every pipe <20% -- the staged structure's serial
// vmcnt->ds_write->barrier->ds_read chain with <=8 waves/CU is the invariant.
// ffn_pool proves register-direct MFMA operands at ~12 waves/CU hides VMEM
// latency fine. So: NO LDS, NO barriers. Both fragments global->register:
//   A: emb fp32, per frag 2x float4 at row (bm*128+wr*64+m*16+l15), col
//      kt*64+kk*32+lg*8; cvt_pk to bf16 at arrival. Each 128B line fully
//      consumed (kk=0 lower half, kk=1 upper), shared by 2 waves via L1.
//   B: B1t bf16 16B/frag. B1t = 1.2MB total -> L2-resident per XCD
//      (XCD swizzle keeps all 6 bn-sharers of a bm-panel on one die).
// Wave tile 64x64 (acc[4][4]); ~140 VGPR, no LDS -> ~3 blocks/CU, 12+ waves.
// Same verified fragment/output conventions as R4-R10.
// ---------------------------------------------------------------------------
__global__ __launch_bounds__(256) void k_gemm1(const float* __restrict__ emb,
    const u16* __restrict__ B1t, const float* __restrict__ Pb, u16* __restrict__ Hi)
{
  const int tid  = threadIdx.x;
  const int lane = tid & 63;
  const int w    = tid >> 6;                    // 0..3
  const int wr = w >> 1, wc = w & 1;            // wave tile: rows wr*64, cols wc*64
  const int L = blockIdx.x;                     // 0..3071, XCD-chunked swizzle
  const int widx = (L & 7) * 384 + (L >> 3);
  const int bm = widx / 6, bn = widx % 6;
  const int l15 = lane & 15, lg = lane >> 4;

  // per-lane fragment base pointers (col base lg*8 folded in)
  const float* aBase[4];
  const u16*   bBase[4];
  #pragma unroll
  for (int m = 0; m < 4; ++m)
    aBase[m] = emb + (size_t)(bm*128 + wr*64 + m*16 + l15) * Tsz + lg*8;
  #pragma unroll
  for (int c = 0; c < 4; ++c)
    bBase[c] = B1t + (size_t)(bn*128 + wc*64 + c*16 + l15) * Tsz + lg*8;

  f32x4 acc[4][4] = {};

  #pragma unroll 1
  for (int kt = 0; kt < 12; ++kt) {
    #pragma unroll
    for (int kk = 0; kk < 2; ++kk) {
      const int kO = kt*64 + kk*32;
      bf16x8 b[4];
      #pragma unroll
      for (int c = 0; c < 4; ++c)
        b[c] = *reinterpret_cast<const bf16x8*>(bBase[c] + kO);
      bf16x8 a[4];
      #pragma unroll
      for (int m = 0; m < 4; ++m) {
        float4 v0 = *reinterpret_cast<const float4*>(aBase[m] + kO);
        float4 v1 = *reinterpret_cast<const float4*>(aBase[m] + kO + 4);
        bf16x8 af;
        af[0] = (__bf16)v0.x; af[1] = (__bf16)v0.y; af[2] = (__bf16)v0.z; af[3] = (__bf16)v0.w;
        af[4] = (__bf16)v1.x; af[5] = (__bf16)v1.y; af[6] = (__bf16)v1.z; af[7] = (__bf16)v1.w;
        a[m] = af;
      }
      __builtin_amdgcn_s_setprio(1);
      #pragma unroll
      for (int m = 0; m < 4; ++m)
        #pragma unroll
        for (int c = 0; c < 4; ++c)
          acc[m][c] = __builtin_amdgcn_mfma_f32_16x16x32_bf16(a[m], b[c], acc[m][c], 0, 0, 0);
      __builtin_amdgcn_s_setprio(0);
    }
  }

  // epilogue: bias + bf16 store (C layout: col=lane&15, row=(lane>>4)*4+j)
  #pragma unroll
  for (int c = 0; c < 4; ++c) {
    int col = bn*128 + wc*64 + c*16 + l15;
    float bias = Pb[col];
    #pragma unroll
    for (int m = 0; m < 4; ++m) {
      int row0 = bm*128 + wr*64 + m*16 + lg*4;
      #pragma unroll
      for (int j = 0; j < 4; ++j)
        Hi[(size_t)(row0 + j)*Ncols + col] = f2bn(acc[m][c][j] + bias);
    }
  }
}

// ---------------------------------------------------------------------------
// Kernel 3 (v5, unchanged): persistent per-(h,b) block, fused FFN + pool.
// W1_h and W2_h staged in LDS; Zb bounce; in-register online softmax.
// ---------------------------------------------------------------------------
__global__ __launch_bounds__(256, 1) void k_ffn_pool(
    const u16* __restrict__ Hi, const u16* __restrict__ W1t, const u16* __restrict__ W2t,
    const float* __restrict__ b1, const float* __restrict__ b2v, const float* __restrict__ mask,
    float* __restrict__ out)
{
  __shared__ u16 W1s[384][104];    // 79872 B
  __shared__ u16 W2s[96][392];     // 75264 B
  __shared__ u16 Zb[4][16][40];    // 5120 B; one bounce slot per wave
  // per-wave merge buffers alias the wave's own Zb slot (1280B >= 1152B)

  const int tid = threadIdx.x, lane = tid & 63, w = tid >> 6;
  const int l15 = lane & 15, lg = lane >> 4;
  const int h = blockIdx.x, b = blockIdx.y;

  const u16* W1h = W1t + (size_t)h * DHID * DH;
  const u16* W2h = W2t + (size_t)h * DH * DHID;
  const float* b1h = b1 + h * DHID;

  for (int i = tid; i < 384*12; i += 256) {
    int r = i / 12, g = i % 12;
    uint4 v = *reinterpret_cast<const uint4*>(W1h + (size_t)r*DH + g*8);
    *reinterpret_cast<uint4*>(&W1s[r][g*8]) = v;
  }
  for (int i = tid; i < 96*48; i += 256) {
    int r = i / 48, g = i % 48;
    uint4 v = *reinterpret_cast<const uint4*>(W2h + (size_t)r*DHID + g*8);
    *reinterpret_cast<uint4*>(&W2s[r][g*8]) = v;
  }
  __syncthreads();

  float b2s[6];
  #pragma unroll
  for (int ct = 0; ct < 6; ++ct) b2s[ct] = b2v[h*DH + ct*16 + l15];

  float Mr[6], Lr[6], Ar[6];
  #pragma unroll
  for (int ct = 0; ct < 6; ++ct) { Mr[ct] = -3.4e38f; Lr[ct] = 0.f; Ar[ct] = 0.f; }

  #pragma unroll 1
  for (int pass = 0; pass < 8; ++pass) {
    const size_t prow = (size_t)b*Ssz + (size_t)w*512 + (size_t)pass*64;

    bf16x8 hifr[4][3];
    #pragma unroll
    for (int s = 0; s < 4; ++s)
      #pragma unroll
      for (int ks = 0; ks < 3; ++ks)
        hifr[s][ks] = *reinterpret_cast<const bf16x8*>(
            Hi + (prow + s*16 + l15)*Ncols + h*DH + ks*32 + lg*8);

    f32x4 lgt[4][6] = {};

    #pragma unroll 2
    for (int c = 0; c < 12; ++c) {
      bf16x8 a1c[2][3];
      #pragma unroll
      for (int t = 0; t < 2; ++t)
        #pragma unroll
        for (int ks = 0; ks < 3; ++ks)
          a1c[t][ks] = *reinterpret_cast<const bf16x8*>(
              &W1s[c*32 + t*16 + l15][ks*32 + lg*8]);
      float4 bc0 = *reinterpret_cast<const float4*>(b1h + c*32 + lg*4);
      float4 bc1 = *reinterpret_cast<const float4*>(b1h + c*32 + 16 + lg*4);
      bf16x8 b2fr[6];
      #pragma unroll
      for (int ct = 0; ct < 6; ++ct)
        b2fr[ct] = *reinterpret_cast<const bf16x8*>(&W2s[ct*16 + l15][c*32 + lg*8]);

      #pragma unroll
      for (int s = 0; s < 4; ++s) {
        f32x4 z0 = {}, z1 = {};
        #pragma unroll
        for (int ks = 0; ks < 3; ++ks) {
          z0 = __builtin_amdgcn_mfma_f32_16x16x32_bf16(a1c[0][ks], hifr[s][ks], z0, 0, 0, 0);
          z1 = __builtin_amdgcn_mfma_f32_16x16x32_bf16(a1c[1][ks], hifr[s][ks], z1, 0, 0, 0);
        }
        bf16x4 p0, p1;
        p0[0] = (__bf16)fmaxf(z0[0] + bc0.x, 0.f);
        p0[1] = (__bf16)fmaxf(z0[1] + bc0.y, 0.f);
        p0[2] = (__bf16)fmaxf(z0[2] + bc0.z, 0.f);
        p0[3] = (__bf16)fmaxf(z0[3] + bc0.w, 0.f);
        p1[0] = (__bf16)fmaxf(z1[0] + bc1.x, 0.f);
        p1[1] = (__bf16)fmaxf(z1[1] + bc1.y, 0.f);
        p1[2] = (__bf16)fmaxf(z1[2] + bc1.z, 0.f);
        p1[3] = (__bf16)fmaxf(z1[3] + bc1.w, 0.f);
        *reinterpret_cast<uint2*>(&Zb[w][l15][lg*4])      = __builtin_bit_cast(uint2, p0);
        *reinterpret_cast<uint2*>(&Zb[w][l15][16 + lg*4]) = __builtin_bit_cast(uint2, p1);
        bf16x8 zf = *reinterpret_cast<const bf16x8*>(&Zb[w][l15][lg*8]);
        #pragma unroll
        for (int ct = 0; ct < 6; ++ct)
          lgt[s][ct] = __builtin_amdgcn_mfma_f32_16x16x32_bf16(zf, b2fr[ct], lgt[s][ct], 0, 0, 0);
      }
    }

    float lmv[4][4];
    #pragma unroll
    for (int s = 0; s < 4; ++s) {
      float4 mk = *reinterpret_cast<const float4*>(&mask[prow + s*16 + lg*4]);
      lmv[s][0] = __logf(mk.x); lmv[s][1] = __logf(mk.y);
      lmv[s][2] = __logf(mk.z); lmv[s][3] = __logf(mk.w);
    }
    float G[4][6][4];
    #pragma unroll
    for (int s = 0; s < 4; ++s)
      #pragma unroll
      for (int ct = 0; ct < 6; ++ct)
        #pragma unroll
        for (int j = 0; j < 4; ++j)
          G[s][ct][j] = b2f(Hi[(prow + s*16 + lg*4 + j)*Ncols + h*DH + ct*16 + l15]);

    #pragma unroll
    for (int ct = 0; ct < 6; ++ct) {
      float av[4][4];
      float m16 = -3.4e38f;
      #pragma unroll
      for (int s = 0; s < 4; ++s)
        #pragma unroll
        for (int j = 0; j < 4; ++j) {
          av[s][j] = lgt[s][ct][j] + b2s[ct] + lmv[s][j];
          m16 = fmaxf(m16, av[s][j]);
        }
      m16 = fmaxf(m16, __shfl_xor(m16, 16));
      m16 = fmaxf(m16, __shfl_xor(m16, 32));
      float l16 = 0.f, a16 = 0.f;
      #pragma unroll
      for (int s = 0; s < 4; ++s)
        #pragma unroll
        for (int j = 0; j < 4; ++j) {
          float p = __expf(av[s][j] - m16);
          l16 += p;
          a16 += p * G[s][ct][j];
        }
      l16 += __shfl_xor(l16, 16); l16 += __shfl_xor(l16, 32);
      a16 += __shfl_xor(a16, 16); a16 += __shfl_xor(a16, 32);
      float M2 = fmaxf(Mr[ct], m16);
      float eo = __expf(Mr[ct] - M2), en = __expf(m16 - M2);
      Lr[ct] = Lr[ct]*eo + l16*en;
      Ar[ct] = Ar[ct]*eo + a16*en;
      Mr[ct] = M2;
    }
  }

  float* mw = reinterpret_cast<float*>(&Zb[w][0][0]);   // 1280B >= 1152B
  if (lane < 16) {
    #pragma unroll
    for (int ct = 0; ct < 6; ++ct) {
      mw[      ct*16 + l15] = Mr[ct];
      mw[ 96 + ct*16 + l15] = Lr[ct];
      mw[192 + ct*16 + l15] = Ar[ct];
    }
  }
  __syncthreads();
  if (tid < 96) {
    const float* m0 = reinterpret_cast<const float*>(&Zb[0][0][0]);
    const float* m1 = reinterpret_cast<const float*>(&Zb[1][0][0]);
    const float* m2 = reinterpret_cast<const float*>(&Zb[2][0][0]);
    const float* m3 = reinterpret_cast<const float*>(&Zb[3][0][0]);
    float m = fmaxf(fmaxf(m0[tid], m1[tid]), fmaxf(m2[tid], m3[tid]));
    float e0 = __expf(m0[tid] - m), e1 = __expf(m1[tid] - m);
    float e2 = __expf(m2[tid] - m), e3 = __expf(m3[tid] - m);
    float l = m0[96+tid]*e0 + m1[96+tid]*e1 + m2[96+tid]*e2 + m3[96+tid]*e3;
    float a = m0[192+tid]*e0 + m1[192+tid]*e1 + m2[192+tid]*e2 + m3[192+tid]*e3;
    out[(size_t)b * Ncols + h*DH + tid] = a / l;
  }
}

// ---------------------------------------------------------------------------
// Workspace layout (bytes), total ~103 MB:
//   Hi  bf16 : 0           (100663296)
//   B1t bf16 : 100663296   (1179648)
//   W1t bf16 : 101842944   (589824)
//   W2t bf16 : 102432768   (589824)
// ---------------------------------------------------------------------------
extern "C" void kernel_launch(void* const* d_in, const int* in_sizes, int n_in,
                              void* d_out, int out_size, void* d_ws, size_t ws_size,
                              hipStream_t stream)
{
  const float* emb  = (const float*)d_in[0];
  const float* mask = (const float*)d_in[1];
  const float* Pw   = (const float*)d_in[2];
  const float* Pb   = (const float*)d_in[3];
  const float* W1w  = (const float*)d_in[4];
  const float* W1b  = (const float*)d_in[5];
  const float* W2w  = (const float*)d_in[6];
  const float* W2b  = (const float*)d_in[7];
  float* out = (float*)d_out;

  char* ws = (char*)d_ws;
  u16*   Hi  = (u16*)(ws);
  u16*   B1t = (u16*)(ws + 100663296ull);
  u16*   W1t = (u16*)(ws + 101842944ull);
  u16*   W2t = (u16*)(ws + 102432768ull);

  k_pack<<<dim3(4608), dim3(256), 0, stream>>>(Pw, W1w, W2w, B1t, W1t, W2t);
  k_gemm1<<<dim3(3072), dim3(256), 0, stream>>>(emb, B1t, Pb, Hi);
  k_ffn_pool<<<dim3(8, 32), dim3(256), 0, stream>>>(Hi, W1t, W2t, W1b, W2b, mask, out);
}

// Round 12
// 287.104 us; speedup vs baseline: 1.8145x; 1.8145x over previous
//
#include <hip/hip_runtime.h>
#include <cstdint>
#include <cstddef>

// Problem constants
#define Bsz   32
#define Ssz   2048
#define Tsz   768
#define NH    8
#define DH    96
#define DHID  384
#define Ncols (NH*DH)       // 768

using u16 = unsigned short;
typedef __bf16 bf16x8 __attribute__((ext_vector_type(8)));
typedef __bf16 bf16x4 __attribute__((ext_vector_type(4)));
typedef float  f32x4  __attribute__((ext_vector_type(4)));

__device__ __forceinline__ u16 f2bn(float f) {
  __bf16 h = (__bf16)f;
  return __builtin_bit_cast(u16, h);
}
__device__ __forceinline__ float b2f(u16 u) {
  return __builtin_bit_cast(float, (uint32_t)u << 16);
}

// ---------------------------------------------------------------------------
// Kernel 1: pack weights to bf16 (transposed, K-contiguous)  [unchanged]
// ---------------------------------------------------------------------------
__global__ __launch_bounds__(256) void k_pack(const float* __restrict__ Pw,
    const float* __restrict__ W1w, const float* __restrict__ W2w,
    u16* __restrict__ B1t, u16* __restrict__ W1t, u16* __restrict__ W2t)
{
  int i = blockIdx.x * 256 + threadIdx.x;
  if (i < 589824) {
    int n = i / 768, k = i % 768;
    int h = n / 96, d = n % 96;
    B1t[i] = f2bn(Pw[(size_t)h*73728 + (size_t)k*96 + d]);
  } else if (i < 589824 + 294912) {
    int j = i - 589824;
    int h = j / 36864, r = j % 36864;
    int n = r / 96, k = r % 96;
    W1t[j] = f2bn(W1w[(size_t)h*36864 + (size_t)k*384 + n]);
  } else if (i < 589824 + 2*294912) {
    int q = i - 589824 - 294912;
    int h = q / 36864, r = q % 36864;
    int n = r / 384, k = r % 384;
    W2t[q] = f2bn(W2w[(size_t)h*36864 + (size_t)k*96 + n]);
  }
}

// ---------------------------------------------------------------------------
// Kernel 2 (v9): Hi = emb @ B1 + P_b.
// R11 post-mortem: zero-LDS direct fragment loads are scattered (16 rows x
// 3KB stride per wave-load) -> TA segment cost, 432us. LDS staging is the
// coalescing device; keep it.
// R12 experiment: OCCUPANCY, un-confounded. R6-R10 all ran at 22% occ
// (LDS-capped, 2 blocks/CU); R9's 45%-occ test was poisoned by forced
// VGPR=64 spills. This version: R10's exact staging (reg-staged A+B, XOR
// swizzle, 0 conflicts, loads of t+1 overlap compute of t) on a SINGLE
// 32KB buffer (2 barriers/kt), NATURAL register allocation (no min-waves
// clamp -> no spills). LDS 32KB -> 5 blocks/CU; VGPR ~88+AGPR -> 3-4
// waves/SIMD. Expect 12-16 waves/CU vs 8.
// ---------------------------------------------------------------------------
__global__ __launch_bounds__(256) void k_gemm1(const float* __restrict__ emb,
    const u16* __restrict__ B1t, const float* __restrict__ Pb, u16* __restrict__ Hi)
{
  __shared__ u16 As[128*64];   // 16 KB bf16 A tile (swizzled chunks)
  __shared__ u16 Bs[128*64];   // 16 KB bf16 B tile (swizzled chunks)
  const int tid  = threadIdx.x;
  const int lane = tid & 63;
  const int w    = tid >> 6;                    // 0..3
  const int wr = w >> 1, wc = w & 1;            // wave tile: rows wr*64, cols wc*64
  const int L = blockIdx.x;                     // 0..3071, XCD-chunked swizzle
  const int widx = (L & 7) * 384 + (L >> 3);
  const int bm = widx / 6, bn = widx % 6;
  const int l15 = lane & 15, lg = lane >> 4;

  // staging geometry: 8 rows x 8 chunks of 16B per wave-issue
  const int srow   = lane >> 3;     // 0..7 (== row & 7 for staged rows)
  const int schunk = lane & 7;      // logical 16B chunk within the row
  const int wchunk = schunk ^ srow; // physical (swizzled) chunk for ds_write

  bf16x8 pa[4];   // A prefetch (converted at arrival)
  bf16x8 pb[4];   // B prefetch (raw 16B)

  auto load_tile = [&](int kt) {
    const int k0 = kt * 64;
    #pragma unroll
    for (int i = 0; i < 4; ++i) {
      const int row = w*32 + i*8 + srow;
      const float* src = emb + (size_t)(bm*128 + row)*Tsz + k0 + schunk*8;
      float4 v0 = *reinterpret_cast<const float4*>(src);
      float4 v1 = *reinterpret_cast<const float4*>(src + 4);
      bf16x8 af;
      af[0] = (__bf16)v0.x; af[1] = (__bf16)v0.y; af[2] = (__bf16)v0.z; af[3] = (__bf16)v0.w;
      af[4] = (__bf16)v1.x; af[5] = (__bf16)v1.y; af[6] = (__bf16)v1.z; af[7] = (__bf16)v1.w;
      pa[i] = af;
    }
    #pragma unroll
    for (int i = 0; i < 4; ++i) {
      const int row = w*32 + i*8 + srow;
      pb[i] = *reinterpret_cast<const bf16x8*>(
          B1t + (size_t)(bn*128 + row)*Tsz + k0 + schunk*8);
    }
  };
  auto write_tile = [&]() {
    #pragma unroll
    for (int i = 0; i < 4; ++i) {
      const int row = w*32 + i*8 + srow;
      *reinterpret_cast<bf16x8*>(&As[row*64 + wchunk*8]) = pa[i];
      *reinterpret_cast<bf16x8*>(&Bs[row*64 + wchunk*8]) = pb[i];
    }
  };

  f32x4 acc[4][4] = {};

  load_tile(0);
  write_tile();
  __syncthreads();

  #pragma unroll 1
  for (int kt = 0; kt < 12; ++kt) {
    if (kt < 11) load_tile(kt + 1);   // VMEM in flight under compute
    __builtin_amdgcn_s_setprio(1);
    #pragma unroll
    for (int kk = 0; kk < 2; ++kk) {
      const int clog = kk*4 + lg;
      bf16x8 b[4];
      #pragma unroll
      for (int c = 0; c < 4; ++c) {
        const int Rb = wc*64 + c*16 + l15;
        b[c] = *reinterpret_cast<const bf16x8*>(&Bs[Rb*64 + (clog ^ (Rb & 7))*8]);
      }
      bf16x8 a[4];
      #pragma unroll
      for (int m = 0; m < 4; ++m) {
        const int R = wr*64 + m*16 + l15;
        a[m] = *reinterpret_cast<const bf16x8*>(&As[R*64 + (clog ^ (R & 7))*8]);
      }
      #pragma unroll
      for (int m = 0; m < 4; ++m)
        #pragma unroll
        for (int c = 0; c < 4; ++c)
          acc[m][c] = __builtin_amdgcn_mfma_f32_16x16x32_bf16(a[m], b[c], acc[m][c], 0, 0, 0);
    }
    __builtin_amdgcn_s_setprio(0);
    __syncthreads();                  // all reads of tile kt complete
    if (kt < 11) {
      write_tile();                   // publish tile kt+1
      __syncthreads();
    }
  }

  // epilogue: bias + bf16 store (C layout: col=lane&15, row=(lane>>4)*4+j)
  #pragma unroll
  for (int c = 0; c < 4; ++c) {
    int col = bn*128 + wc*64 + c*16 + l15;
    float bias = Pb[col];
    #pragma unroll
    for (int m = 0; m < 4; ++m) {
      int row0 = bm*128 + wr*64 + m*16 + lg*4;
      #pragma unroll
      for (int j = 0; j < 4; ++j)
        Hi[(size_t)(row0 + j)*Ncols + col] = f2bn(acc[m][c][j] + bias);
    }
  }
}

// ---------------------------------------------------------------------------
// Kernel 3 (v5, unchanged): persistent per-(h,b) block, fused FFN + pool.
// W1_h and W2_h staged in LDS; Zb bounce; in-register online softmax.
// ---------------------------------------------------------------------------
__global__ __launch_bounds__(256, 1) void k_ffn_pool(
    const u16* __restrict__ Hi, const u16* __restrict__ W1t, const u16* __restrict__ W2t,
    const float* __restrict__ b1, const float* __restrict__ b2v, const float* __restrict__ mask,
    float* __restrict__ out)
{
  __shared__ u16 W1s[384][104];    // 79872 B
  __shared__ u16 W2s[96][392];     // 75264 B
  __shared__ u16 Zb[4][16][40];    // 5120 B; one bounce slot per wave
  // per-wave merge buffers alias the wave's own Zb slot (1280B >= 1152B)

  const int tid = threadIdx.x, lane = tid & 63, w = tid >> 6;
  const int l15 = lane & 15, lg = lane >> 4;
  const int h = blockIdx.x, b = blockIdx.y;

  const u16* W1h = W1t + (size_t)h * DHID * DH;
  const u16* W2h = W2t + (size_t)h * DH * DHID;
  const float* b1h = b1 + h * DHID;

  for (int i = tid; i < 384*12; i += 256) {
    int r = i / 12, g = i % 12;
    uint4 v = *reinterpret_cast<const uint4*>(W1h + (size_t)r*DH + g*8);
    *reinterpret_cast<uint4*>(&W1s[r][g*8]) = v;
  }
  for (int i = tid; i < 96*48; i += 256) {
    int r = i / 48, g = i % 48;
    uint4 v = *reinterpret_cast<const uint4*>(W2h + (size_t)r*DHID + g*8);
    *reinterpret_cast<uint4*>(&W2s[r][g*8]) = v;
  }
  __syncthreads();

  float b2s[6];
  #pragma unroll
  for (int ct = 0; ct < 6; ++ct) b2s[ct] = b2v[h*DH + ct*16 + l15];

  float Mr[6], Lr[6], Ar[6];
  #pragma unroll
  for (int ct = 0; ct < 6; ++ct) { Mr[ct] = -3.4e38f; Lr[ct] = 0.f; Ar[ct] = 0.f; }

  #pragma unroll 1
  for (int pass = 0; pass < 8; ++pass) {
    const size_t prow = (size_t)b*Ssz + (size_t)w*512 + (size_t)pass*64;

    bf16x8 hifr[4][3];
    #pragma unroll
    for (int s = 0; s < 4; ++s)
      #pragma unroll
      for (int ks = 0; ks < 3; ++ks)
        hifr[s][ks] = *reinterpret_cast<const bf16x8*>(
            Hi + (prow + s*16 + l15)*Ncols + h*DH + ks*32 + lg*8);

    f32x4 lgt[4][6] = {};

    #pragma unroll 2
    for (int c = 0; c < 12; ++c) {
      bf16x8 a1c[2][3];
      #pragma unroll
      for (int t = 0; t < 2; ++t)
        #pragma unroll
        for (int ks = 0; ks < 3; ++ks)
          a1c[t][ks] = *reinterpret_cast<const bf16x8*>(
              &W1s[c*32 + t*16 + l15][ks*32 + lg*8]);
      float4 bc0 = *reinterpret_cast<const float4*>(b1h + c*32 + lg*4);
      float4 bc1 = *reinterpret_cast<const float4*>(b1h + c*32 + 16 + lg*4);
      bf16x8 b2fr[6];
      #pragma unroll
      for (int ct = 0; ct < 6; ++ct)
        b2fr[ct] = *reinterpret_cast<const bf16x8*>(&W2s[ct*16 + l15][c*32 + lg*8]);

      #pragma unroll
      for (int s = 0; s < 4; ++s) {
        f32x4 z0 = {}, z1 = {};
        #pragma unroll
        for (int ks = 0; ks < 3; ++ks) {
          z0 = __builtin_amdgcn_mfma_f32_16x16x32_bf16(a1c[0][ks], hifr[s][ks], z0, 0, 0, 0);
          z1 = __builtin_amdgcn_mfma_f32_16x16x32_bf16(a1c[1][ks], hifr[s][ks], z1, 0, 0, 0);
        }
        bf16x4 p0, p1;
        p0[0] = (__bf16)fmaxf(z0[0] + bc0.x, 0.f);
        p0[1] = (__bf16)fmaxf(z0[1] + bc0.y, 0.f);
        p0[2] = (__bf16)fmaxf(z0[2] + bc0.z, 0.f);
        p0[3] = (__bf16)fmaxf(z0[3] + bc0.w, 0.f);
        p1[0] = (__bf16)fmaxf(z1[0] + bc1.x, 0.f);
        p1[1] = (__bf16)fmaxf(z1[1] + bc1.y, 0.f);
        p1[2] = (__bf16)fmaxf(z1[2] + bc1.z, 0.f);
        p1[3] = (__bf16)fmaxf(z1[3] + bc1.w, 0.f);
        *reinterpret_cast<uint2*>(&Zb[w][l15][lg*4])      = __builtin_bit_cast(uint2, p0);
        *reinterpret_cast<uint2*>(&Zb[w][l15][16 + lg*4]) = __builtin_bit_cast(uint2, p1);
        bf16x8 zf = *reinterpret_cast<const bf16x8*>(&Zb[w][l15][lg*8]);
        #pragma unroll
        for (int ct = 0; ct < 6; ++ct)
          lgt[s][ct] = __builtin_amdgcn_mfma_f32_16x16x32_bf16(zf, b2fr[ct], lgt[s][ct], 0, 0, 0);
      }
    }

    float lmv[4][4];
    #pragma unroll
    for (int s = 0; s < 4; ++s) {
      float4 mk = *reinterpret_cast<const float4*>(&mask[prow + s*16 + lg*4]);
      lmv[s][0] = __logf(mk.x); lmv[s][1] = __logf(mk.y);
      lmv[s][2] = __logf(mk.z); lmv[s][3] = __logf(mk.w);
    }
    float G[4][6][4];
    #pragma unroll
    for (int s = 0; s < 4; ++s)
      #pragma unroll
      for (int ct = 0; ct < 6; ++ct)
        #pragma unroll
        for (int j = 0; j < 4; ++j)
          G[s][ct][j] = b2f(Hi[(prow + s*16 + lg*4 + j)*Ncols + h*DH + ct*16 + l15]);

    #pragma unroll
    for (int ct = 0; ct < 6; ++ct) {
      float av[4][4];
      float m16 = -3.4e38f;
      #pragma unroll
      for (int s = 0; s < 4; ++s)
        #pragma unroll
        for (int j = 0; j < 4; ++j) {
          av[s][j] = lgt[s][ct][j] + b2s[ct] + lmv[s][j];
          m16 = fmaxf(m16, av[s][j]);
        }
      m16 = fmaxf(m16, __shfl_xor(m16, 16));
      m16 = fmaxf(m16, __shfl_xor(m16, 32));
      float l16 = 0.f, a16 = 0.f;
      #pragma unroll
      for (int s = 0; s < 4; ++s)
        #pragma unroll
        for (int j = 0; j < 4; ++j) {
          float p = __expf(av[s][j] - m16);
          l16 += p;
          a16 += p * G[s][ct][j];
        }
      l16 += __shfl_xor(l16, 16); l16 += __shfl_xor(l16, 32);
      a16 += __shfl_xor(a16, 16); a16 += __shfl_xor(a16, 32);
      float M2 = fmaxf(Mr[ct], m16);
      float eo = __expf(Mr[ct] - M2), en = __expf(m16 - M2);
      Lr[ct] = Lr[ct]*eo + l16*en;
      Ar[ct] = Ar[ct]*eo + a16*en;
      Mr[ct] = M2;
    }
  }

  float* mw = reinterpret_cast<float*>(&Zb[w][0][0]);   // 1280B >= 1152B
  if (lane < 16) {
    #pragma unroll
    for (int ct = 0; ct < 6; ++ct) {
      mw[      ct*16 + l15] = Mr[ct];
      mw[ 96 + ct*16 + l15] = Lr[ct];
      mw[192 + ct*16 + l15] = Ar[ct];
    }
  }
  __syncthreads();
  if (tid < 96) {
    const float* m0 = reinterpret_cast<const float*>(&Zb[0][0][0]);
    const float* m1 = reinterpret_cast<const float*>(&Zb[1][0][0]);
    const float* m2 = reinterpret_cast<const float*>(&Zb[2][0][0]);
    const float* m3 = reinterpret_cast<const float*>(&Zb[3][0][0]);
    float m = fmaxf(fmaxf(m0[tid], m1[tid]), fmaxf(m2[tid], m3[tid]));
    float e0 = __expf(m0[tid] - m), e1 = __expf(m1[tid] - m);
    float e2 = __expf(m2[tid] - m), e3 = __expf(m3[tid] - m);
    float l = m0[96+tid]*e0 + m1[96+tid]*e1 + m2[96+tid]*e2 + m3[96+tid]*e3;
    float a = m0[192+tid]*e0 + m1[192+tid]*e1 + m2[192+tid]*e2 + m3[192+tid]*e3;
    out[(size_t)b * Ncols + h*DH + tid] = a / l;
  }
}

// ---------------------------------------------------------------------------
// Workspace layout (bytes), total ~103 MB:
//   Hi  bf16 : 0           (100663296)
//   B1t bf16 : 100663296   (1179648)
//   W1t bf16 : 101842944   (589824)
//   W2t bf16 : 102432768   (589824)
// ---------------------------------------------------------------------------
extern "C" void kernel_launch(void* const* d_in, const int* in_sizes, int n_in,
                              void* d_out, int out_size, void* d_ws, size_t ws_size,
                              hipStream_t stream)
{
  const float* emb  = (const float*)d_in[0];
  const float* mask = (const float*)d_in[1];
  const float* Pw   = (const float*)d_in[2];
  const float* Pb   = (const float*)d_in[3];
  const float* W1w  = (const float*)d_in[4];
  const float* W1b  = (const float*)d_in[5];
  const float* W2w  = (const float*)d_in[6];
  const float* W2b  = (const float*)d_in[7];
  float* out = (float*)d_out;

  char* ws = (char*)d_ws;
  u16*   Hi  = (u16*)(ws);
  u16*   B1t = (u16*)(ws + 100663296ull);
  u16*   W1t = (u16*)(ws + 101842944ull);
  u16*   W2t = (u16*)(ws + 102432768ull);

  k_pack<<<dim3(4608), dim3(256), 0, stream>>>(Pw, W1w, W2w, B1t, W1t, W2t);
  k_gemm1<<<dim3(3072), dim3(256), 0, stream>>>(emb, B1t, Pb, Hi);
  k_ffn_pool<<<dim3(8, 32), dim3(256), 0, stream>>>(Hi, W1t, W2t, W1b, W2b, mask, out);
}

// Round 13
// 285.953 us; speedup vs baseline: 1.8218x; 1.0040x over previous
//
#include <hip/hip_runtime.h>
#include <cstdint>
#include <cstddef>

// Problem constants
#define Bsz   32
#define Ssz   2048
#define Tsz   768
#define NH    8
#define DH    96
#define DHID  384
#define Ncols (NH*DH)       // 768

using u16 = unsigned short;
typedef __bf16 bf16x8 __attribute__((ext_vector_type(8)));
typedef __bf16 bf16x4 __attribute__((ext_vector_type(4)));
typedef float  f32x4  __attribute__((ext_vector_type(4)));

__device__ __forceinline__ u16 f2bn(float f) {
  __bf16 h = (__bf16)f;
  return __builtin_bit_cast(u16, h);
}
__device__ __forceinline__ float b2f(u16 u) {
  return __builtin_bit_cast(float, (uint32_t)u << 16);
}

// async global->LDS, 16B per lane; LDS dest = wave-uniform base + lane*16
typedef const __attribute__((address_space(1))) void* gas_t;
typedef __attribute__((address_space(3))) void* las_t;
__device__ __forceinline__ void gload16(const void* g, void* s) {
  __builtin_amdgcn_global_load_lds((gas_t)g, (las_t)s, 16, 0, 0);
}

// ---------------------------------------------------------------------------
// Kernel 0: convert emb fp32 -> bf16 (same [row][k] layout).
// 50331648 elems = 8192 blocks x 256 thr x 3 iters x 8 elems.
// ---------------------------------------------------------------------------
__global__ __launch_bounds__(256) void k_cvt(const float* __restrict__ e,
                                             u16* __restrict__ o)
{
  size_t t = (size_t)blockIdx.x * 256 + threadIdx.x;   // 0..2097151
  #pragma unroll
  for (int it = 0; it < 3; ++it) {
    size_t i = (t + (size_t)it * 2097152) * 8;
    float4 v0 = *reinterpret_cast<const float4*>(e + i);
    float4 v1 = *reinterpret_cast<const float4*>(e + i + 4);
    bf16x8 p;
    p[0] = (__bf16)v0.x; p[1] = (__bf16)v0.y; p[2] = (__bf16)v0.z; p[3] = (__bf16)v0.w;
    p[4] = (__bf16)v1.x; p[5] = (__bf16)v1.y; p[6] = (__bf16)v1.z; p[7] = (__bf16)v1.w;
    *reinterpret_cast<bf16x8*>(o + i) = p;
  }
}

// ---------------------------------------------------------------------------
// Kernel 1: pack weights to bf16 (transposed, K-contiguous)  [unchanged]
// ---------------------------------------------------------------------------
__global__ __launch_bounds__(256) void k_pack(const float* __restrict__ Pw,
    const float* __restrict__ W1w, const float* __restrict__ W2w,
    u16* __restrict__ B1t, u16* __restrict__ W1t, u16* __restrict__ W2t)
{
  int i = blockIdx.x * 256 + threadIdx.x;
  if (i < 589824) {
    int n = i / 768, k = i % 768;
    int h = n / 96, d = n % 96;
    B1t[i] = f2bn(Pw[(size_t)h*73728 + (size_t)k*96 + d]);
  } else if (i < 589824 + 294912) {
    int j = i - 589824;
    int h = j / 36864, r = j % 36864;
    int n = r / 96, k = r % 96;
    W1t[j] = f2bn(W1w[(size_t)h*36864 + (size_t)k*384 + n]);
  } else if (i < 589824 + 2*294912) {
    int q = i - 589824 - 294912;
    int h = q / 36864, r = q % 36864;
    int n = r / 384, k = r % 384;
    W2t[q] = f2bn(W2w[(size_t)h*36864 + (size_t)k*96 + n]);
  }
}

// ---------------------------------------------------------------------------
// Kernel 2 (v10, m97-exact): Hi = embb(bf16) @ B1 + P_b.
// 128x128 tile, BK=64, 4 waves (2x2), wave tile 64x64, acc[4][4].
// BOTH operands staged via global_load_lds width-16 (ladder step-3, +69%):
// no staging registers, no ds_write -> low VGPR -> ~3 blocks/CU; cross-block
// overlap hides the stage->sync->compute serial chain (m97/m114).
// Pre-swizzled SOURCE chunk (lc = (lane&7)^(lane>>3)) + linear LDS dest
// (rule #21); ds_read uses phys = clog ^ (row&7) -- invariant verified R6-R12.
// ---------------------------------------------------------------------------
__global__ __launch_bounds__(256) void k_gemm1(const u16* __restrict__ embb,
    const u16* __restrict__ B1t, const float* __restrict__ Pb, u16* __restrict__ Hi)
{
  __shared__ u16 As[128*64];   // 16 KB bf16 A tile (swizzled chunks)
  __shared__ u16 Bs[128*64];   // 16 KB bf16 B tile (swizzled chunks)
  const int tid  = threadIdx.x;
  const int lane = tid & 63;
  const int w    = tid >> 6;                    // 0..3
  const int wr = w >> 1, wc = w & 1;            // wave tile: rows wr*64, cols wc*64
  const int L = blockIdx.x;                     // 0..3071, XCD-chunked swizzle
  const int widx = (L & 7) * 384 + (L >> 3);
  const int bm = widx / 6, bn = widx % 6;
  const int l15 = lane & 15, lg = lane >> 4;

  const int lrow = lane >> 3;            // row within 8-row issue group
  const int lchk = (lane & 7) ^ lrow;    // pre-swizzled source chunk

  f32x4 acc[4][4] = {};

  #pragma unroll 1
  for (int kt = 0; kt < 12; ++kt) {
    const int k0 = kt * 64;
    // stage tile kt: 4 issues/wave per operand (1KB each, linear LDS dest)
    #pragma unroll
    for (int i = 0; i < 4; ++i) {
      const int r8 = (w*4 + i)*8;        // base row of this issue
      gload16(embb + (size_t)(bm*128 + r8 + lrow)*Tsz + k0 + lchk*8,
              &As[r8*64]);
      gload16(B1t  + (size_t)(bn*128 + r8 + lrow)*Tsz + k0 + lchk*8,
              &Bs[r8*64]);
    }
    __syncthreads();   // compiler drains vmcnt before barrier

    __builtin_amdgcn_s_setprio(1);
    #pragma unroll
    for (int kk = 0; kk < 2; ++kk) {
      const int clog = kk*4 + lg;
      bf16x8 b[4];
      #pragma unroll
      for (int c = 0; c < 4; ++c) {
        const int Rb = wc*64 + c*16 + l15;
        b[c] = *reinterpret_cast<const bf16x8*>(&Bs[Rb*64 + (clog ^ (Rb & 7))*8]);
      }
      bf16x8 a[4];
      #pragma unroll
      for (int m = 0; m < 4; ++m) {
        const int R = wr*64 + m*16 + l15;
        a[m] = *reinterpret_cast<const bf16x8*>(&As[R*64 + (clog ^ (R & 7))*8]);
      }
      #pragma unroll
      for (int m = 0; m < 4; ++m)
        #pragma unroll
        for (int c = 0; c < 4; ++c)
          acc[m][c] = __builtin_amdgcn_mfma_f32_16x16x32_bf16(a[m], b[c], acc[m][c], 0, 0, 0);
    }
    __builtin_amdgcn_s_setprio(0);
    __syncthreads();
  }

  // epilogue: bias + bf16 store (C layout: col=lane&15, row=(lane>>4)*4+j)
  #pragma unroll
  for (int c = 0; c < 4; ++c) {
    int col = bn*128 + wc*64 + c*16 + l15;
    float bias = Pb[col];
    #pragma unroll
    for (int m = 0; m < 4; ++m) {
      int row0 = bm*128 + wr*64 + m*16 + lg*4;
      #pragma unroll
      for (int j = 0; j < 4; ++j)
        Hi[(size_t)(row0 + j)*Ncols + col] = f2bn(acc[m][c][j] + bias);
    }
  }
}

// ---------------------------------------------------------------------------
// Kernel 2-FALLBACK (R10 dbuf version, reads emb fp32) -- used if ws_size
// is too small for the embb buffer. Proven 179us.
// ---------------------------------------------------------------------------
__global__ __launch_bounds__(256, 2) void k_gemm1_fb(const float* __restrict__ emb,
    const u16* __restrict__ B1t, const float* __restrict__ Pb, u16* __restrict__ Hi)
{
  __shared__ u16 As[2][128*64];
  __shared__ u16 Bs[2][128*64];
  const int tid  = threadIdx.x;
  const int lane = tid & 63;
  const int w    = tid >> 6;
  const int wr = w >> 1, wc = w & 1;
  const int L = blockIdx.x;
  const int widx = (L & 7) * 384 + (L >> 3);
  const int bm = widx / 6, bn = widx % 6;
  const int l15 = lane & 15, lg = lane >> 4;

  const int srow   = lane >> 3;
  const int schunk = lane & 7;
  const int wchunk = schunk ^ srow;

  bf16x8 pa[4];
  bf16x8 pb[4];

  auto load_tile = [&](int kt) {
    const int k0 = kt * 64;
    #pragma unroll
    for (int i = 0; i < 4; ++i) {
      const int row = w*32 + i*8 + srow;
      const float* src = emb + (size_t)(bm*128 + row)*Tsz + k0 + schunk*8;
      float4 v0 = *reinterpret_cast<const float4*>(src);
      float4 v1 = *reinterpret_cast<const float4*>(src + 4);
      bf16x8 af;
      af[0] = (__bf16)v0.x; af[1] = (__bf16)v0.y; af[2] = (__bf16)v0.z; af[3] = (__bf16)v0.w;
      af[4] = (__bf16)v1.x; af[5] = (__bf16)v1.y; af[6] = (__bf16)v1.z; af[7] = (__bf16)v1.w;
      pa[i] = af;
    }
    #pragma unroll
    for (int i = 0; i < 4; ++i) {
      const int row = w*32 + i*8 + srow;
      pb[i] = *reinterpret_cast<const bf16x8*>(
          B1t + (size_t)(bn*128 + row)*Tsz + k0 + schunk*8);
    }
  };
  auto write_tile = [&](int buf) {
    #pragma unroll
    for (int i = 0; i < 4; ++i) {
      const int row = w*32 + i*8 + srow;
      *reinterpret_cast<bf16x8*>(&As[buf][row*64 + wchunk*8]) = pa[i];
      *reinterpret_cast<bf16x8*>(&Bs[buf][row*64 + wchunk*8]) = pb[i];
    }
  };

  f32x4 acc[4][4] = {};

  load_tile(0);
  write_tile(0);
  __syncthreads();

  #pragma unroll 1
  for (int kt = 0; kt < 12; ++kt) {
    const int cur = kt & 1;
    if (kt < 11) load_tile(kt + 1);
    __builtin_amdgcn_s_setprio(1);
    #pragma unroll
    for (int kk = 0; kk < 2; ++kk) {
      const int clog = kk*4 + lg;
      bf16x8 b[4];
      #pragma unroll
      for (int c = 0; c < 4; ++c) {
        const int Rb = wc*64 + c*16 + l15;
        b[c] = *reinterpret_cast<const bf16x8*>(&Bs[cur][Rb*64 + (clog ^ (Rb & 7))*8]);
      }
      bf16x8 a[4];
      #pragma unroll
      for (int m = 0; m < 4; ++m) {
        const int R = wr*64 + m*16 + l15;
        a[m] = *reinterpret_cast<const bf16x8*>(&As[cur][R*64 + (clog ^ (R & 7))*8]);
      }
      #pragma unroll
      for (int m = 0; m < 4; ++m)
        #pragma unroll
        for (int c = 0; c < 4; ++c)
          acc[m][c] = __builtin_amdgcn_mfma_f32_16x16x32_bf16(a[m], b[c], acc[m][c], 0, 0, 0);
    }
    __builtin_amdgcn_s_setprio(0);
    if (kt < 11) write_tile(cur ^ 1);
    __syncthreads();
  }

  #pragma unroll
  for (int c = 0; c < 4; ++c) {
    int col = bn*128 + wc*64 + c*16 + l15;
    float bias = Pb[col];
    #pragma unroll
    for (int m = 0; m < 4; ++m) {
      int row0 = bm*128 + wr*64 + m*16 + lg*4;
      #pragma unroll
      for (int j = 0; j < 4; ++j)
        Hi[(size_t)(row0 + j)*Ncols + col] = f2bn(acc[m][c][j] + bias);
    }
  }
}

// ---------------------------------------------------------------------------
// Kernel 3 (v5, unchanged): persistent per-(h,b) block, fused FFN + pool.
// ---------------------------------------------------------------------------
__global__ __launch_bounds__(256, 1) void k_ffn_pool(
    const u16* __restrict__ Hi, const u16* __restrict__ W1t, const u16* __restrict__ W2t,
    const float* __restrict__ b1, const float* __restrict__ b2v, const float* __restrict__ mask,
    float* __restrict__ out)
{
  __shared__ u16 W1s[384][104];    // 79872 B
  __shared__ u16 W2s[96][392];     // 75264 B
  __shared__ u16 Zb[4][16][40];    // 5120 B; one bounce slot per wave

  const int tid = threadIdx.x, lane = tid & 63, w = tid >> 6;
  const int l15 = lane & 15, lg = lane >> 4;
  const int h = blockIdx.x, b = blockIdx.y;

  const u16* W1h = W1t + (size_t)h * DHID * DH;
  const u16* W2h = W2t + (size_t)h * DH * DHID;
  const float* b1h = b1 + h * DHID;

  for (int i = tid; i < 384*12; i += 256) {
    int r = i / 12, g = i % 12;
    uint4 v = *reinterpret_cast<const uint4*>(W1h + (size_t)r*DH + g*8);
    *reinterpret_cast<uint4*>(&W1s[r][g*8]) = v;
  }
  for (int i = tid; i < 96*48; i += 256) {
    int r = i / 48, g = i % 48;
    uint4 v = *reinterpret_cast<const uint4*>(W2h + (size_t)r*DHID + g*8);
    *reinterpret_cast<uint4*>(&W2s[r][g*8]) = v;
  }
  __syncthreads();

  float b2s[6];
  #pragma unroll
  for (int ct = 0; ct < 6; ++ct) b2s[ct] = b2v[h*DH + ct*16 + l15];

  float Mr[6], Lr[6], Ar[6];
  #pragma unroll
  for (int ct = 0; ct < 6; ++ct) { Mr[ct] = -3.4e38f; Lr[ct] = 0.f; Ar[ct] = 0.f; }

  #pragma unroll 1
  for (int pass = 0; pass < 8; ++pass) {
    const size_t prow = (size_t)b*Ssz + (size_t)w*512 + (size_t)pass*64;

    bf16x8 hifr[4][3];
    #pragma unroll
    for (int s = 0; s < 4; ++s)
      #pragma unroll
      for (int ks = 0; ks < 3; ++ks)
        hifr[s][ks] = *reinterpret_cast<const bf16x8*>(
            Hi + (prow + s*16 + l15)*Ncols + h*DH + ks*32 + lg*8);

    f32x4 lgt[4][6] = {};

    #pragma unroll 2
    for (int c = 0; c < 12; ++c) {
      bf16x8 a1c[2][3];
      #pragma unroll
      for (int t = 0; t < 2; ++t)
        #pragma unroll
        for (int ks = 0; ks < 3; ++ks)
          a1c[t][ks] = *reinterpret_cast<const bf16x8*>(
              &W1s[c*32 + t*16 + l15][ks*32 + lg*8]);
      float4 bc0 = *reinterpret_cast<const float4*>(b1h + c*32 + lg*4);
      float4 bc1 = *reinterpret_cast<const float4*>(b1h + c*32 + 16 + lg*4);
      bf16x8 b2fr[6];
      #pragma unroll
      for (int ct = 0; ct < 6; ++ct)
        b2fr[ct] = *reinterpret_cast<const bf16x8*>(&W2s[ct*16 + l15][c*32 + lg*8]);

      #pragma unroll
      for (int s = 0; s < 4; ++s) {
        f32x4 z0 = {}, z1 = {};
        #pragma unroll
        for (int ks = 0; ks < 3; ++ks) {
          z0 = __builtin_amdgcn_mfma_f32_16x16x32_bf16(a1c[0][ks], hifr[s][ks], z0, 0, 0, 0);
          z1 = __builtin_amdgcn_mfma_f32_16x16x32_bf16(a1c[1][ks], hifr[s][ks], z1, 0, 0, 0);
        }
        bf16x4 p0, p1;
        p0[0] = (__bf16)fmaxf(z0[0] + bc0.x, 0.f);
        p0[1] = (__bf16)fmaxf(z0[1] + bc0.y, 0.f);
        p0[2] = (__bf16)fmaxf(z0[2] + bc0.z, 0.f);
        p0[3] = (__bf16)fmaxf(z0[3] + bc0.w, 0.f);
        p1[0] = (__bf16)fmaxf(z1[0] + bc1.x, 0.f);
        p1[1] = (__bf16)fmaxf(z1[1] + bc1.y, 0.f);
        p1[2] = (__bf16)fmaxf(z1[2] + bc1.z, 0.f);
        p1[3] = (__bf16)fmaxf(z1[3] + bc1.w, 0.f);
        *reinterpret_cast<uint2*>(&Zb[w][l15][lg*4])      = __builtin_bit_cast(uint2, p0);
        *reinterpret_cast<uint2*>(&Zb[w][l15][16 + lg*4]) = __builtin_bit_cast(uint2, p1);
        bf16x8 zf = *reinterpret_cast<const bf16x8*>(&Zb[w][l15][lg*8]);
        #pragma unroll
        for (int ct = 0; ct < 6; ++ct)
          lgt[s][ct] = __builtin_amdgcn_mfma_f32_16x16x32_bf16(zf, b2fr[ct], lgt[s][ct], 0, 0, 0);
      }
    }

    float lmv[4][4];
    #pragma unroll
    for (int s = 0; s < 4; ++s) {
      float4 mk = *reinterpret_cast<const float4*>(&mask[prow + s*16 + lg*4]);
      lmv[s][0] = __logf(mk.x); lmv[s][1] = __logf(mk.y);
      lmv[s][2] = __logf(mk.z); lmv[s][3] = __logf(mk.w);
    }
    float G[4][6][4];
    #pragma unroll
    for (int s = 0; s < 4; ++s)
      #pragma unroll
      for (int ct = 0; ct < 6; ++ct)
        #pragma unroll
        for (int j = 0; j < 4; ++j)
          G[s][ct][j] = b2f(Hi[(prow + s*16 + lg*4 + j)*Ncols + h*DH + ct*16 + l15]);

    #pragma unroll
    for (int ct = 0; ct < 6; ++ct) {
      float av[4][4];
      float m16 = -3.4e38f;
      #pragma unroll
      for (int s = 0; s < 4; ++s)
        #pragma unroll
        for (int j = 0; j < 4; ++j) {
          av[s][j] = lgt[s][ct][j] + b2s[ct] + lmv[s][j];
          m16 = fmaxf(m16, av[s][j]);
        }
      m16 = fmaxf(m16, __shfl_xor(m16, 16));
      m16 = fmaxf(m16, __shfl_xor(m16, 32));
      float l16 = 0.f, a16 = 0.f;
      #pragma unroll
      for (int s = 0; s < 4; ++s)
        #pragma unroll
        for (int j = 0; j < 4; ++j) {
          float p = __expf(av[s][j] - m16);
          l16 += p;
          a16 += p * G[s][ct][j];
        }
      l16 += __shfl_xor(l16, 16); l16 += __shfl_xor(l16, 32);
      a16 += __shfl_xor(a16, 16); a16 += __shfl_xor(a16, 32);
      float M2 = fmaxf(Mr[ct], m16);
      float eo = __expf(Mr[ct] - M2), en = __expf(m16 - M2);
      Lr[ct] = Lr[ct]*eo + l16*en;
      Ar[ct] = Ar[ct]*eo + a16*en;
      Mr[ct] = M2;
    }
  }

  float* mw = reinterpret_cast<float*>(&Zb[w][0][0]);   // 1280B >= 1152B
  if (lane < 16) {
    #pragma unroll
    for (int ct = 0; ct < 6; ++ct) {
      mw[      ct*16 + l15] = Mr[ct];
      mw[ 96 + ct*16 + l15] = Lr[ct];
      mw[192 + ct*16 + l15] = Ar[ct];
    }
  }
  __syncthreads();
  if (tid < 96) {
    const float* m0 = reinterpret_cast<const float*>(&Zb[0][0][0]);
    const float* m1 = reinterpret_cast<const float*>(&Zb[1][0][0]);
    const float* m2 = reinterpret_cast<const float*>(&Zb[2][0][0]);
    const float* m3 = reinterpret_cast<const float*>(&Zb[3][0][0]);
    float m = fmaxf(fmaxf(m0[tid], m1[tid]), fmaxf(m2[tid], m3[tid]));
    float e0 = __expf(m0[tid] - m), e1 = __expf(m1[tid] - m);
    float e2 = __expf(m2[tid] - m), e3 = __expf(m3[tid] - m);
    float l = m0[96+tid]*e0 + m1[96+tid]*e1 + m2[96+tid]*e2 + m3[96+tid]*e3;
    float a = m0[192+tid]*e0 + m1[192+tid]*e1 + m2[192+tid]*e2 + m3[192+tid]*e3;
    out[(size_t)b * Ncols + h*DH + tid] = a / l;
  }
}

// ---------------------------------------------------------------------------
// Workspace layouts:
// BIG (ws >= 203685888 B ~ 194.3MB):
//   embb bf16 : 0           (100663296)
//   Hi   bf16 : 100663296   (100663296)
//   B1t  bf16 : 201326592   (1179648)
//   W1t  bf16 : 202506240   (589824)
//   W2t  bf16 : 203096064   (589824)
// FALLBACK (R10 layout, ~103MB): Hi@0, B1t@100663296, W1t@101842944, W2t@102432768
// ---------------------------------------------------------------------------
extern "C" void kernel_launch(void* const* d_in, const int* in_sizes, int n_in,
                              void* d_out, int out_size, void* d_ws, size_t ws_size,
                              hipStream_t stream)
{
  const float* emb  = (const float*)d_in[0];
  const float* mask = (const float*)d_in[1];
  const float* Pw   = (const float*)d_in[2];
  const float* Pb   = (const float*)d_in[3];
  const float* W1w  = (const float*)d_in[4];
  const float* W1b  = (const float*)d_in[5];
  const float* W2w  = (const float*)d_in[6];
  const float* W2b  = (const float*)d_in[7];
  float* out = (float*)d_out;

  char* ws = (char*)d_ws;
  if (ws_size >= 203685888ull) {
    u16* embb = (u16*)(ws);
    u16* Hi   = (u16*)(ws + 100663296ull);
    u16* B1t  = (u16*)(ws + 201326592ull);
    u16* W1t  = (u16*)(ws + 202506240ull);
    u16* W2t  = (u16*)(ws + 203096064ull);
    k_cvt <<<dim3(8192), dim3(256), 0, stream>>>(emb, embb);
    k_pack<<<dim3(4608), dim3(256), 0, stream>>>(Pw, W1w, W2w, B1t, W1t, W2t);
    k_gemm1<<<dim3(3072), dim3(256), 0, stream>>>(embb, B1t, Pb, Hi);
    k_ffn_pool<<<dim3(8, 32), dim3(256), 0, stream>>>(Hi, W1t, W2t, W1b, W2b, mask, out);
  } else {
    u16* Hi  = (u16*)(ws);
    u16* B1t = (u16*)(ws + 100663296ull);
    u16* W1t = (u16*)(ws + 101842944ull);
    u16* W2t = (u16*)(ws + 102432768ull);
    k_pack<<<dim3(4608), dim3(256), 0, stream>>>(Pw, W1w, W2w, B1t, W1t, W2t);
    k_gemm1_fb<<<dim3(3072), dim3(256), 0, stream>>>(emb, B1t, Pb, Hi);
    k_ffn_pool<<<dim3(8, 32), dim3(256), 0, stream>>>(Hi, W1t, W2t, W1b, W2b, mask, out);
  }
}

// Round 14
// 254.547 us; speedup vs baseline: 2.0466x; 1.1234x over previous
//
#include <hip/hip_runtime.h>
#include <cstdint>
#include <cstddef>

// Problem constants
#define Bsz   32
#define Ssz   2048
#define Tsz   768
#define NH    8
#define DH    96
#define DHID  384
#define Ncols (NH*DH)       // 768

using u16 = unsigned short;
typedef __bf16 bf16x8 __attribute__((ext_vector_type(8)));
typedef __bf16 bf16x4 __attribute__((ext_vector_type(4)));
typedef float  f32x4  __attribute__((ext_vector_type(4)));

__device__ __forceinline__ u16 f2bn(float f) {
  __bf16 h = (__bf16)f;
  return __builtin_bit_cast(u16, h);
}
__device__ __forceinline__ float b2f(u16 u) {
  return __builtin_bit_cast(float, (uint32_t)u << 16);
}

// async global->LDS, 16B per lane; LDS dest = wave-uniform base + lane*16
typedef const __attribute__((address_space(1))) void* gas_t;
typedef __attribute__((address_space(3))) void* las_t;
__device__ __forceinline__ void gload16(const void* g, void* s) {
  __builtin_amdgcn_global_load_lds((gas_t)g, (las_t)s, 16, 0, 0);
}

// ---------------------------------------------------------------------------
// Kernel 0: convert emb fp32 -> bf16 (same [row][k] layout).
// ---------------------------------------------------------------------------
__global__ __launch_bounds__(256) void k_cvt(const float* __restrict__ e,
                                             u16* __restrict__ o)
{
  size_t t = (size_t)blockIdx.x * 256 + threadIdx.x;   // 0..2097151
  #pragma unroll
  for (int it = 0; it < 3; ++it) {
    size_t i = (t + (size_t)it * 2097152) * 8;
    float4 v0 = *reinterpret_cast<const float4*>(e + i);
    float4 v1 = *reinterpret_cast<const float4*>(e + i + 4);
    bf16x8 p;
    p[0] = (__bf16)v0.x; p[1] = (__bf16)v0.y; p[2] = (__bf16)v0.z; p[3] = (__bf16)v0.w;
    p[4] = (__bf16)v1.x; p[5] = (__bf16)v1.y; p[6] = (__bf16)v1.z; p[7] = (__bf16)v1.w;
    *reinterpret_cast<bf16x8*>(o + i) = p;
  }
}

// ---------------------------------------------------------------------------
// Kernel 1 (v2): pack weights to bf16.
//   B1t[n][k] row-major (unchanged, for gemm1).
//   W1f/W2f: FRAGMENT-SEQUENTIAL 16B-chunk order so ffn LDS reads are
//   base + lane*16 (sequential, zero-conflict, zero-pad):
//     W1 chunk CI = ((c*2+t)*3+ks)*64 + lane holds W1[h][n=c*32+t*16+l15]
//                   [k=ks*32+lg*8 .. +7]   (lane = lg*16+l15)
//     W2 chunk CI = (c*6+ct)*64 + lane holds W2[h][n=ct*16+l15]
//                   [k=c*32+lg*8 .. +7]
// ---------------------------------------------------------------------------
__global__ __launch_bounds__(256) void k_pack(const float* __restrict__ Pw,
    const float* __restrict__ W1w, const float* __restrict__ W2w,
    u16* __restrict__ B1t, u16* __restrict__ W1f, u16* __restrict__ W2f)
{
  int i = blockIdx.x * 256 + threadIdx.x;
  if (i < 589824) {
    int n = i / 768, k = i % 768;
    int h = n / 96, d = n % 96;
    B1t[i] = f2bn(Pw[(size_t)h*73728 + (size_t)k*96 + d]);
  } else if (i < 589824 + 294912) {
    int j = i - 589824;
    int h = j / 36864, r = j % 36864;
    int CI = r / 8, e = r % 8;
    int lane = CI % 64, ci2 = CI / 64;
    int ks = ci2 % 3, ct2 = ci2 / 3;
    int t = ct2 % 2, c = ct2 / 2;
    int l15 = lane & 15, lg = lane >> 4;
    int n = c*32 + t*16 + l15;
    int k = ks*32 + lg*8 + e;
    W1f[j] = f2bn(W1w[(size_t)h*36864 + (size_t)k*384 + n]);
  } else if (i < 589824 + 2*294912) {
    int q = i - 589824 - 294912;
    int h = q / 36864, r = q % 36864;
    int CI = r / 8, e = r % 8;
    int lane = CI % 64, ci2 = CI / 64;
    int ct = ci2 % 6, c = ci2 / 6;
    int l15 = lane & 15, lg = lane >> 4;
    int n = ct*16 + l15;
    int k = c*32 + lg*8 + e;
    W2f[q] = f2bn(W2w[(size_t)h*36864 + (size_t)k*96 + n]);
  }
}

// ---------------------------------------------------------------------------
// Kernel 2 (v10, m97-exact, unchanged from R13): Hi = embb(bf16) @ B1 + P_b.
// ---------------------------------------------------------------------------
__global__ __launch_bounds__(256) void k_gemm1(const u16* __restrict__ embb,
    const u16* __restrict__ B1t, const float* __restrict__ Pb, u16* __restrict__ Hi)
{
  __shared__ u16 As[128*64];   // 16 KB bf16 A tile (swizzled chunks)
  __shared__ u16 Bs[128*64];   // 16 KB bf16 B tile (swizzled chunks)
  const int tid  = threadIdx.x;
  const int lane = tid & 63;
  const int w    = tid >> 6;                    // 0..3
  const int wr = w >> 1, wc = w & 1;            // wave tile: rows wr*64, cols wc*64
  const int L = blockIdx.x;                     // 0..3071, XCD-chunked swizzle
  const int widx = (L & 7) * 384 + (L >> 3);
  const int bm = widx / 6, bn = widx % 6;
  const int l15 = lane & 15, lg = lane >> 4;

  const int lrow = lane >> 3;            // row within 8-row issue group
  const int lchk = (lane & 7) ^ lrow;    // pre-swizzled source chunk

  f32x4 acc[4][4] = {};

  #pragma unroll 1
  for (int kt = 0; kt < 12; ++kt) {
    const int k0 = kt * 64;
    #pragma unroll
    for (int i = 0; i < 4; ++i) {
      const int r8 = (w*4 + i)*8;        // base row of this issue
      gload16(embb + (size_t)(bm*128 + r8 + lrow)*Tsz + k0 + lchk*8,
              &As[r8*64]);
      gload16(B1t  + (size_t)(bn*128 + r8 + lrow)*Tsz + k0 + lchk*8,
              &Bs[r8*64]);
    }
    __syncthreads();   // compiler drains vmcnt before barrier

    __builtin_amdgcn_s_setprio(1);
    #pragma unroll
    for (int kk = 0; kk < 2; ++kk) {
      const int clog = kk*4 + lg;
      bf16x8 b[4];
      #pragma unroll
      for (int c = 0; c < 4; ++c) {
        const int Rb = wc*64 + c*16 + l15;
        b[c] = *reinterpret_cast<const bf16x8*>(&Bs[Rb*64 + (clog ^ (Rb & 7))*8]);
      }
      bf16x8 a[4];
      #pragma unroll
      for (int m = 0; m < 4; ++m) {
        const int R = wr*64 + m*16 + l15;
        a[m] = *reinterpret_cast<const bf16x8*>(&As[R*64 + (clog ^ (R & 7))*8]);
      }
      #pragma unroll
      for (int m = 0; m < 4; ++m)
        #pragma unroll
        for (int c = 0; c < 4; ++c)
          acc[m][c] = __builtin_amdgcn_mfma_f32_16x16x32_bf16(a[m], b[c], acc[m][c], 0, 0, 0);
    }
    __builtin_amdgcn_s_setprio(0);
    __syncthreads();
  }

  // epilogue: bias + bf16 store (C layout: col=lane&15, row=(lane>>4)*4+j)
  #pragma unroll
  for (int c = 0; c < 4; ++c) {
    int col = bn*128 + wc*64 + c*16 + l15;
    float bias = Pb[col];
    #pragma unroll
    for (int m = 0; m < 4; ++m) {
      int row0 = bm*128 + wr*64 + m*16 + lg*4;
      #pragma unroll
      for (int j = 0; j < 4; ++j)
        Hi[(size_t)(row0 + j)*Ncols + col] = f2bn(acc[m][c][j] + bias);
    }
  }
}

// ---------------------------------------------------------------------------
// Kernel 2-FALLBACK (R10 dbuf, reads emb fp32) -- if ws too small for embb.
// ---------------------------------------------------------------------------
__global__ __launch_bounds__(256, 2) void k_gemm1_fb(const float* __restrict__ emb,
    const u16* __restrict__ B1t, const float* __restrict__ Pb, u16* __restrict__ Hi)
{
  __shared__ u16 As[2][128*64];
  __shared__ u16 Bs[2][128*64];
  const int tid  = threadIdx.x;
  const int lane = tid & 63;
  const int w    = tid >> 6;
  const int wr = w >> 1, wc = w & 1;
  const int L = blockIdx.x;
  const int widx = (L & 7) * 384 + (L >> 3);
  const int bm = widx / 6, bn = widx % 6;
  const int l15 = lane & 15, lg = lane >> 4;

  const int srow   = lane >> 3;
  const int schunk = lane & 7;
  const int wchunk = schunk ^ srow;

  bf16x8 pa[4];
  bf16x8 pb[4];

  auto load_tile = [&](int kt) {
    const int k0 = kt * 64;
    #pragma unroll
    for (int i = 0; i < 4; ++i) {
      const int row = w*32 + i*8 + srow;
      const float* src = emb + (size_t)(bm*128 + row)*Tsz + k0 + schunk*8;
      float4 v0 = *reinterpret_cast<const float4*>(src);
      float4 v1 = *reinterpret_cast<const float4*>(src + 4);
      bf16x8 af;
      af[0] = (__bf16)v0.x; af[1] = (__bf16)v0.y; af[2] = (__bf16)v0.z; af[3] = (__bf16)v0.w;
      af[4] = (__bf16)v1.x; af[5] = (__bf16)v1.y; af[6] = (__bf16)v1.z; af[7] = (__bf16)v1.w;
      pa[i] = af;
    }
    #pragma unroll
    for (int i = 0; i < 4; ++i) {
      const int row = w*32 + i*8 + srow;
      pb[i] = *reinterpret_cast<const bf16x8*>(
          B1t + (size_t)(bn*128 + row)*Tsz + k0 + schunk*8);
    }
  };
  auto write_tile = [&](int buf) {
    #pragma unroll
    for (int i = 0; i < 4; ++i) {
      const int row = w*32 + i*8 + srow;
      *reinterpret_cast<bf16x8*>(&As[buf][row*64 + wchunk*8]) = pa[i];
      *reinterpret_cast<bf16x8*>(&Bs[buf][row*64 + wchunk*8]) = pb[i];
    }
  };

  f32x4 acc[4][4] = {};

  load_tile(0);
  write_tile(0);
  __syncthreads();

  #pragma unroll 1
  for (int kt = 0; kt < 12; ++kt) {
    const int cur = kt & 1;
    if (kt < 11) load_tile(kt + 1);
    __builtin_amdgcn_s_setprio(1);
    #pragma unroll
    for (int kk = 0; kk < 2; ++kk) {
      const int clog = kk*4 + lg;
      bf16x8 b[4];
      #pragma unroll
      for (int c = 0; c < 4; ++c) {
        const int Rb = wc*64 + c*16 + l15;
        b[c] = *reinterpret_cast<const bf16x8*>(&Bs[cur][Rb*64 + (clog ^ (Rb & 7))*8]);
      }
      bf16x8 a[4];
      #pragma unroll
      for (int m = 0; m < 4; ++m) {
        const int R = wr*64 + m*16 + l15;
        a[m] = *reinterpret_cast<const bf16x8*>(&As[cur][R*64 + (clog ^ (R & 7))*8]);
      }
      #pragma unroll
      for (int m = 0; m < 4; ++m)
        #pragma unroll
        for (int c = 0; c < 4; ++c)
          acc[m][c] = __builtin_amdgcn_mfma_f32_16x16x32_bf16(a[m], b[c], acc[m][c], 0, 0, 0);
    }
    __builtin_amdgcn_s_setprio(0);
    if (kt < 11) write_tile(cur ^ 1);
    __syncthreads();
  }

  #pragma unroll
  for (int c = 0; c < 4; ++c) {
    int col = bn*128 + wc*64 + c*16 + l15;
    float bias = Pb[col];
    #pragma unroll
    for (int m = 0; m < 4; ++m) {
      int row0 = bm*128 + wr*64 + m*16 + lg*4;
      #pragma unroll
      for (int j = 0; j < 4; ++j)
        Hi[(size_t)(row0 + j)*Ncols + col] = f2bn(acc[m][c][j] + bias);
    }
  }
}

// ---------------------------------------------------------------------------
// Kernel 3 (v6): persistent per-(h,b) block, fused FFN + pool.
// R13 post-mortem: 160KB LDS -> 1 block/CU -> 1 wave/SIMD: zero latency
// hiding; 9.5M bank conflicts from padded-stride W1s/W2s reads.
// v6: (a) weights staged from FRAGMENT-SEQUENTIAL global layout -> LDS reads
// are base+lane*16 (0 conflicts, 0 pad; W1s+W2s = 144KB); (b) 512 threads =
// 8 waves, each owns 256 rows (4 passes) -> 2 waves/SIMD latency hiding.
// LDS total 157.7KB. Per-wave inner code identical to v5 (verified).
// ---------------------------------------------------------------------------
__global__ __launch_bounds__(512, 1) void k_ffn_pool(
    const u16* __restrict__ Hi, const u16* __restrict__ W1f, const u16* __restrict__ W2f,
    const float* __restrict__ b1, const float* __restrict__ b2v, const float* __restrict__ mask,
    float* __restrict__ out)
{
  __shared__ u16 W1s[36864];       // 73728 B, fragment-sequential
  __shared__ u16 W2s[36864];       // 73728 B, fragment-sequential
  __shared__ u16 Zb[8][16][40];    // 10240 B; one bounce slot per wave

  const int tid = threadIdx.x, lane = tid & 63, w = tid >> 6;   // w = 0..7
  const int l15 = lane & 15, lg = lane >> 4;
  const int h = blockIdx.x, b = blockIdx.y;

  const u16* W1h = W1f + (size_t)h * DHID * DH;
  const u16* W2h = W2f + (size_t)h * DH * DHID;
  const float* b1h = b1 + h * DHID;

  // stage both weight arrays: linear 16B-chunk copies (4608 chunks each)
  for (int i = tid; i < 4608; i += 512) {
    *reinterpret_cast<uint4*>(&W1s[i*8]) = *reinterpret_cast<const uint4*>(W1h + i*8);
    *reinterpret_cast<uint4*>(&W2s[i*8]) = *reinterpret_cast<const uint4*>(W2h + i*8);
  }
  __syncthreads();

  float b2s[6];
  #pragma unroll
  for (int ct = 0; ct < 6; ++ct) b2s[ct] = b2v[h*DH + ct*16 + l15];

  float Mr[6], Lr[6], Ar[6];
  #pragma unroll
  for (int ct = 0; ct < 6; ++ct) { Mr[ct] = -3.4e38f; Lr[ct] = 0.f; Ar[ct] = 0.f; }

  #pragma unroll 1
  for (int pass = 0; pass < 4; ++pass) {
    const size_t prow = (size_t)b*Ssz + (size_t)w*256 + (size_t)pass*64;

    bf16x8 hifr[4][3];
    #pragma unroll
    for (int s = 0; s < 4; ++s)
      #pragma unroll
      for (int ks = 0; ks < 3; ++ks)
        hifr[s][ks] = *reinterpret_cast<const bf16x8*>(
            Hi + (prow + s*16 + l15)*Ncols + h*DH + ks*32 + lg*8);

    f32x4 lgt[4][6] = {};

    #pragma unroll 2
    for (int c = 0; c < 12; ++c) {
      // W1 A-frags: sequential LDS (chunk = ((c*2+t)*3+ks)*64 + lane)
      bf16x8 a1c[2][3];
      #pragma unroll
      for (int t = 0; t < 2; ++t)
        #pragma unroll
        for (int ks = 0; ks < 3; ++ks)
          a1c[t][ks] = *reinterpret_cast<const bf16x8*>(
              &W1s[(((c*2 + t)*3 + ks)*64 + lane)*8]);
      float4 bc0 = *reinterpret_cast<const float4*>(b1h + c*32 + lg*4);
      float4 bc1 = *reinterpret_cast<const float4*>(b1h + c*32 + 16 + lg*4);
      // W2 B-frags: sequential LDS (chunk = (c*6+ct)*64 + lane)
      bf16x8 b2fr[6];
      #pragma unroll
      for (int ct = 0; ct < 6; ++ct)
        b2fr[ct] = *reinterpret_cast<const bf16x8*>(
            &W2s[((c*6 + ct)*64 + lane)*8]);

      #pragma unroll
      for (int s = 0; s < 4; ++s) {
        f32x4 z0 = {}, z1 = {};
        #pragma unroll
        for (int ks = 0; ks < 3; ++ks) {
          z0 = __builtin_amdgcn_mfma_f32_16x16x32_bf16(a1c[0][ks], hifr[s][ks], z0, 0, 0, 0);
          z1 = __builtin_amdgcn_mfma_f32_16x16x32_bf16(a1c[1][ks], hifr[s][ks], z1, 0, 0, 0);
        }
        bf16x4 p0, p1;
        p0[0] = (__bf16)fmaxf(z0[0] + bc0.x, 0.f);
        p0[1] = (__bf16)fmaxf(z0[1] + bc0.y, 0.f);
        p0[2] = (__bf16)fmaxf(z0[2] + bc0.z, 0.f);
        p0[3] = (__bf16)fmaxf(z0[3] + bc0.w, 0.f);
        p1[0] = (__bf16)fmaxf(z1[0] + bc1.x, 0.f);
        p1[1] = (__bf16)fmaxf(z1[1] + bc1.y, 0.f);
        p1[2] = (__bf16)fmaxf(z1[2] + bc1.z, 0.f);
        p1[3] = (__bf16)fmaxf(z1[3] + bc1.w, 0.f);
        *reinterpret_cast<uint2*>(&Zb[w][l15][lg*4])      = __builtin_bit_cast(uint2, p0);
        *reinterpret_cast<uint2*>(&Zb[w][l15][16 + lg*4]) = __builtin_bit_cast(uint2, p1);
        bf16x8 zf = *reinterpret_cast<const bf16x8*>(&Zb[w][l15][lg*8]);
        #pragma unroll
        for (int ct = 0; ct < 6; ++ct)
          lgt[s][ct] = __builtin_amdgcn_mfma_f32_16x16x32_bf16(zf, b2fr[ct], lgt[s][ct], 0, 0, 0);
      }
    }

    float lmv[4][4];
    #pragma unroll
    for (int s = 0; s < 4; ++s) {
      float4 mk = *reinterpret_cast<const float4*>(&mask[prow + s*16 + lg*4]);
      lmv[s][0] = __logf(mk.x); lmv[s][1] = __logf(mk.y);
      lmv[s][2] = __logf(mk.z); lmv[s][3] = __logf(mk.w);
    }
    float G[4][6][4];
    #pragma unroll
    for (int s = 0; s < 4; ++s)
      #pragma unroll
      for (int ct = 0; ct < 6; ++ct)
        #pragma unroll
        for (int j = 0; j < 4; ++j)
          G[s][ct][j] = b2f(Hi[(prow + s*16 + lg*4 + j)*Ncols + h*DH + ct*16 + l15]);

    #pragma unroll
    for (int ct = 0; ct < 6; ++ct) {
      float av[4][4];
      float m16 = -3.4e38f;
      #pragma unroll
      for (int s = 0; s < 4; ++s)
        #pragma unroll
        for (int j = 0; j < 4; ++j) {
          av[s][j] = lgt[s][ct][j] + b2s[ct] + lmv[s][j];
          m16 = fmaxf(m16, av[s][j]);
        }
      m16 = fmaxf(m16, __shfl_xor(m16, 16));
      m16 = fmaxf(m16, __shfl_xor(m16, 32));
      float l16 = 0.f, a16 = 0.f;
      #pragma unroll
      for (int s = 0; s < 4; ++s)
        #pragma unroll
        for (int j = 0; j < 4; ++j) {
          float p = __expf(av[s][j] - m16);
          l16 += p;
          a16 += p * G[s][ct][j];
        }
      l16 += __shfl_xor(l16, 16); l16 += __shfl_xor(l16, 32);
      a16 += __shfl_xor(a16, 16); a16 += __shfl_xor(a16, 32);
      float M2 = fmaxf(Mr[ct], m16);
      float eo = __expf(Mr[ct] - M2), en = __expf(m16 - M2);
      Lr[ct] = Lr[ct]*eo + l16*en;
      Ar[ct] = Ar[ct]*eo + a16*en;
      Mr[ct] = M2;
    }
  }

  // ---- block-level merge: each wave writes into ITS OWN Zb slot (alias) ----
  float* mw = reinterpret_cast<float*>(&Zb[w][0][0]);   // 1280B >= 1152B
  if (lane < 16) {
    #pragma unroll
    for (int ct = 0; ct < 6; ++ct) {
      mw[      ct*16 + l15] = Mr[ct];
      mw[ 96 + ct*16 + l15] = Lr[ct];
      mw[192 + ct*16 + l15] = Ar[ct];
    }
  }
  __syncthreads();
  if (tid < 96) {
    float m = -3.4e38f;
    #pragma unroll
    for (int q = 0; q < 8; ++q) {
      const float* mq = reinterpret_cast<const float*>(&Zb[q][0][0]);
      m = fmaxf(m, mq[tid]);
    }
    float l = 0.f, a = 0.f;
    #pragma unroll
    for (int q = 0; q < 8; ++q) {
      const float* mq = reinterpret_cast<const float*>(&Zb[q][0][0]);
      float sc = __expf(mq[tid] - m);
      l += mq[96 + tid] * sc;
      a += mq[192 + tid] * sc;
    }
    out[(size_t)b * Ncols + h*DH + tid] = a / l;
  }
}

// ---------------------------------------------------------------------------
// Workspace layouts:
// BIG (ws >= 203685888 B ~ 194.3MB):
//   embb bf16 : 0           (100663296)
//   Hi   bf16 : 100663296   (100663296)
//   B1t  bf16 : 201326592   (1179648)
//   W1f  bf16 : 202506240   (589824)
//   W2f  bf16 : 203096064   (589824)
// FALLBACK (~103MB): Hi@0, B1t@100663296, W1f@101842944, W2f@102432768
// ---------------------------------------------------------------------------
extern "C" void kernel_launch(void* const* d_in, const int* in_sizes, int n_in,
                              void* d_out, int out_size, void* d_ws, size_t ws_size,
                              hipStream_t stream)
{
  const float* emb  = (const float*)d_in[0];
  const float* mask = (const float*)d_in[1];
  const float* Pw   = (const float*)d_in[2];
  const float* Pb   = (const float*)d_in[3];
  const float* W1w  = (const float*)d_in[4];
  const float* W1b  = (const float*)d_in[5];
  const float* W2w  = (const float*)d_in[6];
  const float* W2b  = (const float*)d_in[7];
  float* out = (float*)d_out;

  char* ws = (char*)d_ws;
  if (ws_size >= 203685888ull) {
    u16* embb = (u16*)(ws);
    u16* Hi   = (u16*)(ws + 100663296ull);
    u16* B1t  = (u16*)(ws + 201326592ull);
    u16* W1f  = (u16*)(ws + 202506240ull);
    u16* W2f  = (u16*)(ws + 203096064ull);
    k_cvt <<<dim3(8192), dim3(256), 0, stream>>>(emb, embb);
    k_pack<<<dim3(4608), dim3(256), 0, stream>>>(Pw, W1w, W2w, B1t, W1f, W2f);
    k_gemm1<<<dim3(3072), dim3(256), 0, stream>>>(embb, B1t, Pb, Hi);
    k_ffn_pool<<<dim3(8, 32), dim3(512), 0, stream>>>(Hi, W1f, W2f, W1b, W2b, mask, out);
  } else {
    u16* Hi  = (u16*)(ws);
    u16* B1t = (u16*)(ws + 100663296ull);
    u16* W1f = (u16*)(ws + 101842944ull);
    u16* W2f = (u16*)(ws + 102432768ull);
    k_pack<<<dim3(4608), dim3(256), 0, stream>>>(Pw, W1w, W2w, B1t, W1f, W2f);
    k_gemm1_fb<<<dim3(3072), dim3(256), 0, stream>>>(emb, B1t, Pb, Hi);
    k_ffn_pool<<<dim3(8, 32), dim3(512), 0, stream>>>(Hi, W1f, W2f, W1b, W2b, mask, out);
  }
}